// Round 1
// baseline (276.938 us; speedup 1.0000x reference)
//
#include <hip/hip_runtime.h>
#include <cstdint>
#include <cstddef>

#define BATCH 32
#define NCLS 81
#define NFG 80
#define NBOX 15130
#define TOPK 200
#define NTASK (BATCH * NFG)
#define NEG_INF -1e30f
#define CAP 2048
#define SCORE_THR 0.05f
#define CRITERIA 0.45f

// ---------------------------------------------------------------- K1: decode + softmax stats
__global__ __launch_bounds__(256) void k1_decode(
    const float* __restrict__ bboxes,   // [B,4,N]
    const float* __restrict__ scores,   // [B,C,N]
    const float* __restrict__ dboxes,   // [N,4]
    float4* __restrict__ ltrb,          // [B*N]
    float2* __restrict__ stats)         // [B*N] (max, denom)
{
    int g = blockIdx.x * blockDim.x + threadIdx.x;
    if (g >= BATCH * NBOX) return;
    int b = g / NBOX;
    int n = g - b * NBOX;

    // decode: xy = (0.1*b)*dwh + dxy ; wh = exp(0.2*b)*dwh ; ltrb = xy -/+ 0.5*wh
    const float* bb = bboxes + (size_t)b * 4 * NBOX + n;
    float bx = bb[0];
    float by = bb[NBOX];
    float bw = bb[2 * (size_t)NBOX];
    float bh = bb[3 * (size_t)NBOX];
    float4 d = reinterpret_cast<const float4*>(dboxes)[n];  // cx, cy, w, h
    float xx = __fadd_rn(__fmul_rn(__fmul_rn(0.1f, bx), d.z), d.x);
    float yy = __fadd_rn(__fmul_rn(__fmul_rn(0.1f, by), d.w), d.y);
    float wx = __fmul_rn(expf(__fmul_rn(0.2f, bw)), d.z);
    float wy = __fmul_rn(expf(__fmul_rn(0.2f, bh)), d.w);
    float4 o;
    o.x = __fsub_rn(xx, __fmul_rn(0.5f, wx));
    o.y = __fsub_rn(yy, __fmul_rn(0.5f, wy));
    o.z = __fadd_rn(xx, __fmul_rn(0.5f, wx));
    o.w = __fadd_rn(yy, __fmul_rn(0.5f, wy));
    ltrb[g] = o;

    // softmax stats over 81 classes (held in registers; sequential sum)
    const float* sc = scores + (size_t)b * NCLS * NBOX + n;
    float vals[NCLS];
#pragma unroll
    for (int c = 0; c < NCLS; ++c) vals[c] = sc[(size_t)c * NBOX];
    float m = vals[0];
#pragma unroll
    for (int c = 1; c < NCLS; ++c) m = fmaxf(m, vals[c]);
    float s = 0.0f;
#pragma unroll
    for (int c = 0; c < NCLS; ++c) s = __fadd_rn(s, expf(__fsub_rn(vals[c], m)));
    stats[g] = make_float2(m, s);
}

// ---------------------------------------------------------------- K2: per-(image,class) top-K + NMS
__global__ __launch_bounds__(256) void k2_nms(
    const float* __restrict__ scores,       // [B,C,N]
    const float4* __restrict__ ltrb,        // [B*N]
    const float2* __restrict__ stats,       // [B*N]
    float* __restrict__ cls_scores,         // [NTASK*200]
    float4* __restrict__ cls_boxes)         // [NTASK*200]
{
    const int t = blockIdx.x;       // task = b*80 + (c-1)
    const int b = t / NFG;
    const int c = t - b * NFG + 1;  // class 1..80
    const int tid = threadIdx.x;

    __shared__ unsigned long long cand[CAP];
    __shared__ int cnt;
    __shared__ float4 sbox[TOPK];
    __shared__ float sarea[TOPK];
    __shared__ float sscore[TOPK];
    __shared__ unsigned long long mrow[TOPK][4];
    __shared__ unsigned long long keepw[4];

    for (int i = tid; i < CAP; i += 256) cand[i] = 0ULL;
    if (tid == 0) cnt = 0;
    __syncthreads();

    // Phase A: collect candidates with prob > SCORE_THR
    const float* srow = scores + ((size_t)b * NCLS + c) * NBOX;
    const float2* st = stats + (size_t)b * NBOX;
    for (int n = tid; n < NBOX; n += 256) {
        float2 md = st[n];
        float p = __fdiv_rn(expf(__fsub_rn(srow[n], md.x)), md.y);
        if (p > SCORE_THR) {
            int pos = atomicAdd(&cnt, 1);
            if (pos < CAP) {
                unsigned int pb = __float_as_uint(p);
                cand[pos] = ((unsigned long long)pb << 32) |
                            (unsigned long long)(0xFFFFFFFFu - (unsigned)n);
            }
        }
    }
    __syncthreads();

    int cl = min(cnt, CAP);

    // Phase B: bitonic sort descending (score desc, idx asc) over next-pow2(cl)
    unsigned sz = 2;
    while (sz < (unsigned)cl) sz <<= 1;
    for (unsigned k = 2; k <= sz; k <<= 1) {
        for (unsigned j = k >> 1; j > 0; j >>= 1) {
            for (unsigned i = tid; i < sz; i += 256) {
                unsigned ixj = i ^ j;
                if (ixj > i) {
                    unsigned long long a = cand[i], bb2 = cand[ixj];
                    bool desc = ((i & k) == 0);
                    if (desc ? (a < bb2) : (a > bb2)) { cand[i] = bb2; cand[ixj] = a; }
                }
            }
            __syncthreads();
        }
    }

    const int mk = min(cl, TOPK);

    // Phase C: gather boxes for top-mk
    if (tid < mk) {
        unsigned long long key = cand[tid];
        unsigned n = 0xFFFFFFFFu - (unsigned)(key & 0xFFFFFFFFull);
        float4 bx = ltrb[(size_t)b * NBOX + n];
        sbox[tid] = bx;
        sarea[tid] = __fmul_rn(__fsub_rn(bx.z, bx.x), __fsub_rn(bx.w, bx.y));
        sscore[tid] = __uint_as_float((unsigned)(key >> 32));
    }
    __syncthreads();

    // Phase D: suppression bitmask rows (IoU with reference's unclamped deltas)
    if (tid < mk) {
        float4 bi = sbox[tid];
        float ai = sarea[tid];
#pragma unroll
        for (int q = 0; q < 4; ++q) {
            unsigned long long w = 0ULL;
            int j0 = q * 64;
            int j1 = min(mk, j0 + 64);
            for (int j2 = max(tid + 1, j0); j2 < j1; ++j2) {
                float4 bj = sbox[j2];
                float ltx = fmaxf(bi.x, bj.x), lty = fmaxf(bi.y, bj.y);
                float rbx = fminf(bi.z, bj.z), rby = fminf(bi.w, bj.w);
                float dx = __fsub_rn(rbx, ltx), dy = __fsub_rn(rby, lty);
                float inter = __fmul_rn(dx, dy);
                float uni = __fsub_rn(__fadd_rn(ai, sarea[j2]), inter);
                float iou = __fdiv_rn(inter, uni);
                if (iou >= CRITERIA) w |= 1ULL << (j2 - j0);
            }
            mrow[tid][q] = w;
        }
    }
    __syncthreads();

    // Phase E: greedy sequential pass (single thread, bitmask words)
    if (tid == 0) {
        auto maskBits = [](int r) -> unsigned long long {
            if (r <= 0) return 0ULL;
            if (r >= 64) return ~0ULL;
            return (1ULL << r) - 1ULL;
        };
        unsigned long long kw0 = maskBits(mk);
        unsigned long long kw1 = maskBits(mk - 64);
        unsigned long long kw2 = maskBits(mk - 128);
        unsigned long long kw3 = maskBits(mk - 192);
#define GREEDY_WORD(KW, BASE)                                                     \
        for (int bit = 0; bit < 64; ++bit) {                                      \
            int i = (BASE) + bit;                                                 \
            if (i >= mk) break;                                                   \
            if ((KW >> bit) & 1ULL) {                                             \
                kw0 &= ~mrow[i][0]; kw1 &= ~mrow[i][1];                           \
                kw2 &= ~mrow[i][2]; kw3 &= ~mrow[i][3];                           \
            }                                                                     \
        }
        GREEDY_WORD(kw0, 0)
        GREEDY_WORD(kw1, 64)
        GREEDY_WORD(kw2, 128)
        GREEDY_WORD(kw3, 192)
#undef GREEDY_WORD
        keepw[0] = kw0; keepw[1] = kw1; keepw[2] = kw2; keepw[3] = kw3;
    }
    __syncthreads();

    // Phase F: write per-class results
    if (tid < TOPK) {
        float s = NEG_INF;
        if (tid < mk && ((keepw[tid >> 6] >> (tid & 63)) & 1ULL)) s = sscore[tid];
        cls_scores[(size_t)t * TOPK + tid] = s;
        if (tid < mk) cls_boxes[(size_t)t * TOPK + tid] = sbox[tid];
    }
}

// ---------------------------------------------------------------- K3: per-image global top-200
__device__ __forceinline__ int blockReduceSum(int x, int* red, int tid) {
    __syncthreads();  // protect red[] from previous use
    red[tid] = x;
    __syncthreads();
    for (int off = 128; off > 0; off >>= 1) {
        if (tid < off) red[tid] += red[tid + off];
        __syncthreads();
    }
    return red[0];
}

__global__ __launch_bounds__(256) void k3_topk(
    const float* __restrict__ cls_scores,   // [B*80*200]
    const float4* __restrict__ cls_boxes,   // [B*80*200]
    float* __restrict__ out)                // boxes [B*200*4] | labels [B*200] | scores [B*200]
{
    const int b = blockIdx.x;
    const int tid = threadIdx.x;
    const int NFLAT = NFG * TOPK;           // 16000
    const int PER = 63;                      // ceil(16000/256)

    __shared__ unsigned long long sel[512];
    __shared__ int scnt;
    __shared__ int red[256];

    const float* S = cls_scores + (size_t)b * NFLAT;
    float v[PER];
#pragma unroll
    for (int i = 0; i < PER; ++i) {
        int j = i * 256 + tid;
        v[i] = (j < NFLAT) ? S[j] : NEG_INF;
    }

    // valid count
    int lc = 0;
#pragma unroll
    for (int i = 0; i < PER; ++i) lc += (v[i] > -1e29f) ? 1 : 0;
    int validCount = blockReduceSum(lc, red, tid);

    // binary search (float bit space) for the 200th-largest value
    unsigned thrBits = 0;
    if (validCount > TOPK) {
        unsigned lo = 0, hi = 0x7F800000u;
        while (lo < hi) {
            unsigned mid = (lo + hi) >> 1;
            float mf = __uint_as_float(mid);
            int c2 = 0;
#pragma unroll
            for (int i = 0; i < PER; ++i) c2 += (v[i] > mf) ? 1 : 0;
            int tot = blockReduceSum(c2, red, tid);
            if (tot < TOPK) hi = mid; else lo = mid + 1;
        }
        thrBits = lo;
    }

    __syncthreads();
    if (tid == 0) scnt = 0;
    for (int i = tid; i < 512; i += 256) sel[i] = 0ULL;
    __syncthreads();

    const bool useGE = (validCount > TOPK);
    const float thrF = __uint_as_float(thrBits);
#pragma unroll
    for (int i = 0; i < PER; ++i) {
        int j = i * 256 + tid;
        bool take = useGE ? (v[i] >= thrF) : (v[i] > -1e29f);
        if (j < NFLAT && take) {
            int pos = atomicAdd(&scnt, 1);
            if (pos < 512) {
                sel[pos] = ((unsigned long long)__float_as_uint(v[i]) << 32) |
                           (unsigned long long)(0xFFFFFFFFu - (unsigned)j);
            }
        }
    }
    __syncthreads();
    int total = min(min(scnt, 512), TOPK);

    // bitonic sort 512 descending
    for (unsigned k = 2; k <= 512; k <<= 1) {
        for (unsigned j = k >> 1; j > 0; j >>= 1) {
            for (unsigned i = tid; i < 512; i += 256) {
                unsigned ixj = i ^ j;
                if (ixj > i) {
                    unsigned long long a = sel[i], bb2 = sel[ixj];
                    bool desc = ((i & k) == 0);
                    if (desc ? (a < bb2) : (a > bb2)) { sel[i] = bb2; sel[ixj] = a; }
                }
            }
            __syncthreads();
        }
    }

    // write outputs
    if (tid < TOPK) {
        size_t ob = (size_t)b * TOPK + tid;
        float4 bx = make_float4(0.f, 0.f, 0.f, 0.f);
        float lab = 0.f, sc2 = 0.f;
        if (tid < total) {
            unsigned long long key = sel[tid];
            unsigned j = 0xFFFFFFFFu - (unsigned)(key & 0xFFFFFFFFull);
            sc2 = __uint_as_float((unsigned)(key >> 32));
            unsigned cls = j / TOPK;
            unsigned within = j - cls * TOPK;
            bx = cls_boxes[((size_t)b * NFG + cls) * TOPK + within];
            lab = (float)(cls + 1);
        }
        reinterpret_cast<float4*>(out)[ob] = bx;
        out[(size_t)BATCH * TOPK * 4 + ob] = lab;
        out[(size_t)BATCH * TOPK * 4 + (size_t)BATCH * TOPK + ob] = sc2;
    }
}

// ---------------------------------------------------------------- launch
extern "C" void kernel_launch(void* const* d_in, const int* in_sizes, int n_in,
                              void* d_out, int out_size, void* d_ws, size_t ws_size,
                              hipStream_t stream) {
    (void)in_sizes; (void)n_in; (void)out_size; (void)ws_size;
    const float* bboxes = (const float*)d_in[0];   // [32,4,15130]
    const float* scores = (const float*)d_in[1];   // [32,81,15130]
    const float* dboxes = (const float*)d_in[2];   // [1,15130,4]
    float* out = (float*)d_out;

    char* ws = (char*)d_ws;
    float4* ltrb       = (float4*)(ws);                                   // 7,746,560 B
    float2* stats      = (float2*)(ws + 7746560);                         // 3,873,280 B
    float*  cls_scores = (float*) (ws + 7746560 + 3873280);               // 2,048,000 B
    float4* cls_boxes  = (float4*)(ws + 7746560 + 3873280 + 2048000);     // 8,192,000 B

    int g1 = (BATCH * NBOX + 255) / 256;
    k1_decode<<<g1, 256, 0, stream>>>(bboxes, scores, dboxes, ltrb, stats);
    k2_nms<<<NTASK, 256, 0, stream>>>(scores, ltrb, stats, cls_scores, cls_boxes);
    k3_topk<<<BATCH, 256, 0, stream>>>(cls_scores, cls_boxes, out);
}